// Round 1
// baseline (697.482 us; speedup 1.0000x reference)
//
#include <hip/hip_runtime.h>
#include <cfloat>

#define BATCH 4
#define P 8192
#define C 64
#define KNN 16
#define NPTS (BATCH * P)        // 32768
#define NEDGE (NPTS * KNN)      // 524288
#define EPSV 1e-5f
#define SLOPE 0.2f
#define NQ 2                    // column-range split per row-tile
#define QCOLS (P / NQ)          // 4096 cols per block
#define NCH (QCOLS / 64)        // 64 chunks
#define CAP 32                  // steady append slots per row per chunk

typedef __attribute__((ext_vector_type(8))) short bf16x8;
typedef __attribute__((ext_vector_type(16))) float f32x16;

// ---------------- workspace layout (float element offsets) ----------------
// U      : [NPTS][C]   @ 0          (2097152)   written AFTER knn
// V      : [NPTS][C]   @ 2097152    (2097152)   written AFTER knn
// xfh/xfm/xfl bf16 frags alias U/V region (dead after knn)
// sq     : [NPTS]      @ 4194304    (32768)
// stats  : [128]       @ 4227072
// sshift : [128]       @ 4227200
// idx    : int[NEDGE]  @ 4227328    (524288)
// pv     : [NPTS][NQ][16] float @ 4751616 (1048576)
// pi     : [NPTS][NQ][16] int   @ 5800192 (1048576)
// total = 6848768 floats = 26.1 MB

__device__ __forceinline__ unsigned short f2bf(float f) {
    unsigned u = __float_as_uint(f);
    u += 0x7FFFu + ((u >> 16) & 1u);
    return (unsigned short)(u >> 16);
}
__device__ __forceinline__ float bf2f(unsigned short s) {
    return __uint_as_float(((unsigned)s) << 16);
}

// ---------------------------------------------------------------------------
// K0: fragment-layout 3-way bf16 split of x + exact fp32 row norms.
// ---------------------------------------------------------------------------
__global__ void prep_frag(const float* __restrict__ x, uint4* __restrict__ xfh,
                          uint4* __restrict__ xfm, uint4* __restrict__ xfl,
                          float* __restrict__ sq) {
    __shared__ float part[32][9];
    int tid = threadIdx.x;
    int ptl = tid >> 3, j8 = tid & 7;
    int g = blockIdx.x;
    int p = g * 32 + ptl;
    const float4* xp = (const float4*)(x + (size_t)p * C + j8 * 8);
    float4 a = xp[0], b = xp[1];
    float v[8] = {a.x, a.y, a.z, a.w, b.x, b.y, b.z, b.w};
    unsigned short hs[8], ms[8], ls[8];
    float ssum = 0.f;
#pragma unroll
    for (int e = 0; e < 8; ++e) {
        float xv = v[e];
        ssum = fmaf(xv, xv, ssum);
        unsigned short h = f2bf(xv);
        float r1 = xv - bf2f(h);
        unsigned short m = f2bf(r1);
        float r2 = r1 - bf2f(m);
        unsigned short l = f2bf(r2);
        hs[e] = h; ms[e] = m; ls[e] = l;
    }
    int dst = (g * 4 + (j8 >> 1)) * 64 + ptl + 32 * (j8 & 1);
    uint4 ph, pm, pl;
    ph.x = (unsigned)hs[0] | ((unsigned)hs[1] << 16);
    ph.y = (unsigned)hs[2] | ((unsigned)hs[3] << 16);
    ph.z = (unsigned)hs[4] | ((unsigned)hs[5] << 16);
    ph.w = (unsigned)hs[6] | ((unsigned)hs[7] << 16);
    pm.x = (unsigned)ms[0] | ((unsigned)ms[1] << 16);
    pm.y = (unsigned)ms[2] | ((unsigned)ms[3] << 16);
    pm.z = (unsigned)ms[4] | ((unsigned)ms[5] << 16);
    pm.w = (unsigned)ms[6] | ((unsigned)ms[7] << 16);
    pl.x = (unsigned)ls[0] | ((unsigned)ls[1] << 16);
    pl.y = (unsigned)ls[2] | ((unsigned)ls[3] << 16);
    pl.z = (unsigned)ls[4] | ((unsigned)ls[5] << 16);
    pl.w = (unsigned)ls[6] | ((unsigned)ls[7] << 16);
    xfh[dst] = ph; xfm[dst] = pm; xfl[dst] = pl;
    part[ptl][j8] = ssum;
    __syncthreads();
    if (j8 == 0) {
        float s = 0.f;
#pragma unroll
        for (int k = 0; k < 8; ++k) s += part[ptl][k];
        sq[p] = s;
    }
}

// ---------------------------------------------------------------------------
// K1: KNN with distributed ballot top-16 + pipelined merge.
//
// r7 redesign (from rocprof: VALUBusy 50% / MfmaUtil 19.5% — merge-bound):
//  * top-16 per row held ONE VALUE PER LANE across a 16-lane group
//    (wave w, group g owns rows w*16+g*4 .. +3, processed unrolled).
//    Insert = ballot(tv==worst) -> lowest lane swaps -> 4x shfl_xor max
//    reduce (~17 VALU) vs the old serial register-array insert (~90 VALU
//    on 16/64 lanes). idL LDS array eliminated (ids live in registers).
//  * merge of chunk c-1 runs BEFORE barrier A of chunk c, after the MFMA
//    issue — it fills the in-wave MFMA drain instead of serializing after
//    the epilogue. Append buffers double-buffered:
//      R0 = bufv0/bufi0 (CAP=32), R1 = r1pool (slotted 64-wide for chunks
//      0-2, aliased as buf1v/buf1i for odd steady chunks).
//    Thresholds (worstL) are stale by exactly one chunk — same as before,
//    only affects append count, never correctness.
//  * chunks 0-2 write all 64 scores slotted (threshold too loose to bound
//    appends); chunks >=3 append under worstL into CAP=32 slots. At chunk
//    3 appends ~ Binom(64, 16/192): mean 5.3, sigma 2.2 -> CAP=32 is +12
//    sigma; slot is clamped so overflow is memory-safe.
// LDS = 8192+8192+17408+256+512 = 34.6 KB (< 40 KB -> 4 blocks/CU LDS-wise).
// ---------------------------------------------------------------------------
__global__ __launch_bounds__(256, 4) void knn_kernel(const uint4* __restrict__ xfh,
                                                     const uint4* __restrict__ xfm,
                                                     const uint4* __restrict__ xfl,
                                                     const float* __restrict__ sq,
                                                     float* __restrict__ pv,
                                                     int* __restrict__ pi) {
    __shared__ float bufv0[64 * CAP];     // R0 values (even steady chunks)
    __shared__ int   bufi0[64 * CAP];     // R0 ids
    __shared__ float r1pool[64 * 68];     // R1: slotted (stride 68 = 16B align) / buf1 alias
    __shared__ float worstL[64];
    __shared__ int   cntA[2][64];

    float* buf1v = r1pool;                       // [0 .. 2047]
    int*   buf1i = (int*)(r1pool + 64 * CAP);    // [2048 .. 4095] (pool has 4352)

    int tid = threadIdx.x;
    int b = blockIdx.x & 3;              // batch -> XCDs {b, b+4}: frags L2-resident
    int t = blockIdx.x >> 2;
    int tile = t & 127;
    int half = t >> 7;
    int bglob = b * P;
    int r0 = tile * 64;
    int colbase = half * QCOLS;
    int w = tid >> 6, lane = tid & 63;
    int wr = w & 1, wc = w >> 1;
    int g = lane >> 4, gl = lane & 15;
    unsigned long long gmask = 0xFFFFull << (g * 16);
    int myrow0 = w * 16 + g * 4;         // this group's 4 rows

    if (tid < 128) ((int*)cntA)[tid] = 0;

    // persistent A fragments for this wave's 32 rows
    int gA = ((bglob + r0) >> 5) + wr;
    bf16x8 Ah[4], Am[4], Al[4];
#pragma unroll
    for (int kk = 0; kk < 4; ++kk) {
        Ah[kk] = __builtin_bit_cast(bf16x8, xfh[(gA * 4 + kk) * 64 + lane]);
        Am[kk] = __builtin_bit_cast(bf16x8, xfm[(gA * 4 + kk) * 64 + lane]);
        Al[kk] = __builtin_bit_cast(bf16x8, xfl[(gA * 4 + kk) * 64 + lane]);
    }

    // distributed top-16 state: lane gl holds one entry per owned row
    float tvq[4], wq[4];
    int tiq[4];
#pragma unroll
    for (int rr = 0; rr < 4; ++rr) { tvq[rr] = FLT_MAX; wq[rr] = FLT_MAX; tiq[rr] = 0; }

    int rbase = wr * 32 + 4 * (lane >> 5);   // row of reg: rbase+(reg&3)+8*(reg>>2)
    int colq = wc * 32 + (lane & 31);        // this lane's column within chunk
    __syncthreads();

    for (int chunk = 0; chunk < NCH; ++chunk) {
        int c0 = colbase + chunk * 64;
        int gB = ((bglob + c0) >> 5) + wc;
        bf16x8 Bh[4], Bm[4], Bl[4];
#pragma unroll
        for (int kk = 0; kk < 4; ++kk) {
            Bh[kk] = __builtin_bit_cast(bf16x8, xfh[(gB * 4 + kk) * 64 + lane]);
            Bm[kk] = __builtin_bit_cast(bf16x8, xfm[(gB * 4 + kk) * 64 + lane]);
            Bl[kk] = __builtin_bit_cast(bf16x8, xfl[(gB * 4 + kk) * 64 + lane]);
        }
        float sc = sq[bglob + c0 + colq];

        f32x16 acc0, acc1;
#pragma unroll
        for (int i = 0; i < 16; ++i) { acc0[i] = 0.f; acc1[i] = 0.f; }
#pragma unroll
        for (int kk = 0; kk < 4; ++kk) {
            acc0 = __builtin_amdgcn_mfma_f32_32x32x16_bf16(Ah[kk], Bh[kk], acc0, 0, 0, 0);
            acc1 = __builtin_amdgcn_mfma_f32_32x32x16_bf16(Ah[kk], Bm[kk], acc1, 0, 0, 0);
            acc0 = __builtin_amdgcn_mfma_f32_32x32x16_bf16(Am[kk], Bh[kk], acc0, 0, 0, 0);
            acc1 = __builtin_amdgcn_mfma_f32_32x32x16_bf16(Am[kk], Bm[kk], acc1, 0, 0, 0);
            acc0 = __builtin_amdgcn_mfma_f32_32x32x16_bf16(Ah[kk], Bl[kk], acc0, 0, 0, 0);
            acc1 = __builtin_amdgcn_mfma_f32_32x32x16_bf16(Al[kk], Bh[kk], acc1, 0, 0, 0);
        }

        // ---- merge chunk-1 candidates (acc-independent: overlaps MFMA drain) ----
        if (chunk >= 1) {
            if (chunk <= 3) {
                // merging a slotted chunk (0,1,2): n=64, id = base + slot
                int idbase0 = bglob + colbase + (chunk - 1) * 64;
#pragma unroll
                for (int rr = 0; rr < 4; ++rr) {
                    int row = myrow0 + rr;
                    float tv = tvq[rr], worst = wq[rr];
                    int ti = tiq[rr];
                    const float* bv = &r1pool[row * 68];
                    for (int k4 = 0; k4 < 64; k4 += 4) {
                        float4 s4 = *(const float4*)(bv + k4);
#pragma unroll
                        for (int e = 0; e < 4; ++e) {
                            float s = (e == 0) ? s4.x : (e == 1) ? s4.y : (e == 2) ? s4.z : s4.w;
                            if (s < worst) {   // group-uniform condition
                                unsigned long long m = __ballot(tv == worst) & gmask;
                                if (lane == (int)__builtin_ctzll(m)) { tv = s; ti = idbase0 + k4 + e; }
                                float mx = tv;
                                mx = fmaxf(mx, __shfl_xor(mx, 1));
                                mx = fmaxf(mx, __shfl_xor(mx, 2));
                                mx = fmaxf(mx, __shfl_xor(mx, 4));
                                mx = fmaxf(mx, __shfl_xor(mx, 8));
                                worst = mx;
                            }
                        }
                    }
                    tvq[rr] = tv; tiq[rr] = ti; wq[rr] = worst;
                    if (gl == 0) worstL[row] = worst;
                }
            } else {
                // steady merge: appended buffer of chunk-1 (parity = chunk&1)
                int mb = chunk & 1;
                const float* mv = mb ? buf1v : bufv0;
                const int*   mi = mb ? buf1i : bufi0;
#pragma unroll
                for (int rr = 0; rr < 4; ++rr) {
                    int row = myrow0 + rr;
                    float tv = tvq[rr], worst = wq[rr];
                    int ti = tiq[rr];
                    int n = cntA[mb][row]; n = (n > CAP) ? CAP : n;
                    const float* bv = mv + row * CAP;
                    const int*   bi = mi + row * CAP;
                    for (int k = 0; k < n; ++k) {
                        float s = bv[k];
                        if (s < worst) {
                            unsigned long long m = __ballot(tv == worst) & gmask;
                            if (lane == (int)__builtin_ctzll(m)) { tv = s; ti = bi[k]; }
                            float mx = tv;
                            mx = fmaxf(mx, __shfl_xor(mx, 1));
                            mx = fmaxf(mx, __shfl_xor(mx, 2));
                            mx = fmaxf(mx, __shfl_xor(mx, 4));
                            mx = fmaxf(mx, __shfl_xor(mx, 8));
                            worst = mx;
                        }
                    }
                    tvq[rr] = tv; tiq[rr] = ti; wq[rr] = worst;
                    if (gl == 0) worstL[row] = worst;
                    if (gl == 1) cntA[mb][row] = 0;
                }
            }
            __syncthreads();  // (A) worstL fresh, merged buffer free for reuse
        }

        // ---- epilogue: slotted write (chunks 0-2) or thresholded append ----
        if (chunk <= 2) {
#pragma unroll
            for (int reg = 0; reg < 16; ++reg) {
                float s = fmaf(-2.f, acc0[reg] + acc1[reg], sc);
                int row = rbase + (reg & 3) + 8 * (reg >> 2);
                r1pool[row * 68 + colq] = s;
            }
        } else {
            int ab = (chunk - 3) & 1;
            float* av = ab ? buf1v : bufv0;
            int*   ai = ab ? buf1i : bufi0;
            float4 twA[4];
#pragma unroll
            for (int g4 = 0; g4 < 4; ++g4)
                twA[g4] = *(const float4*)&worstL[rbase + 8 * g4];
            int colg = bglob + c0 + colq;
#pragma unroll
            for (int reg = 0; reg < 16; ++reg) {
                float s = fmaf(-2.f, acc0[reg] + acc1[reg], sc);
                float tW = ((const float*)&twA[reg >> 2])[reg & 3];
                if (s < tW) {
                    int row = rbase + (reg & 3) + 8 * (reg >> 2);
                    int slot = atomicAdd(&cntA[ab][row], 1);
                    if (slot < CAP) { av[row * CAP + slot] = s; ai[row * CAP + slot] = colg; }
                }
            }
        }
        __syncthreads();  // (B) appends visible for next iteration's merge
    }

    // ---- tail merge: last chunk's appends (parity NCH&1 == 0 -> R0) ----
    {
        int mb = NCH & 1;
        const float* mv = mb ? buf1v : bufv0;
        const int*   mi = mb ? buf1i : bufi0;
#pragma unroll
        for (int rr = 0; rr < 4; ++rr) {
            int row = myrow0 + rr;
            float tv = tvq[rr], worst = wq[rr];
            int ti = tiq[rr];
            int n = cntA[mb][row]; n = (n > CAP) ? CAP : n;
            const float* bv = mv + row * CAP;
            const int*   bi = mi + row * CAP;
            for (int k = 0; k < n; ++k) {
                float s = bv[k];
                if (s < worst) {
                    unsigned long long m = __ballot(tv == worst) & gmask;
                    if (lane == (int)__builtin_ctzll(m)) { tv = s; ti = bi[k]; }
                    float mx = tv;
                    mx = fmaxf(mx, __shfl_xor(mx, 1));
                    mx = fmaxf(mx, __shfl_xor(mx, 2));
                    mx = fmaxf(mx, __shfl_xor(mx, 4));
                    mx = fmaxf(mx, __shfl_xor(mx, 8));
                    worst = mx;
                }
            }
            tvq[rr] = tv; tiq[rr] = ti;
        }
    }

    // ---- output: lane gl writes its entry for each owned row ----
#pragma unroll
    for (int rr = 0; rr < 4; ++rr) {
        int row = myrow0 + rr;
        size_t o = (((size_t)(bglob + r0 + row)) * NQ + half) * KNN;
        pv[o + gl] = tvq[rr];
        pi[o + gl] = tiq[rr];
    }
}

// ---------------------------------------------------------------------------
// K1b: merge NQ=2 partial top-16 lists per row -> final idx.
// ---------------------------------------------------------------------------
__global__ void merge_kernel(const float* __restrict__ pv, const int* __restrict__ pi,
                             int* __restrict__ idx_out) {
    __shared__ float mv[128 * 33];
    __shared__ int   mi[128 * 33];
    int tid = threadIdx.x;
    int lr = tid & 127, q = tid >> 7;
    int row = blockIdx.x * 128 + lr;
    size_t o = ((size_t)row * NQ + q) * KNN;
#pragma unroll
    for (int j = 0; j < 16; ++j) {
        mv[lr * 33 + q * 16 + j] = pv[o + j];
        mi[lr * 33 + q * 16 + j] = pi[o + j];
    }
    __syncthreads();
    if (tid < 128) {
        float tv[16];
        int ti[16];
        float worst = FLT_MAX;
#pragma unroll
        for (int j = 0; j < 16; ++j) { tv[j] = FLT_MAX; ti[j] = 0; }
        for (int e = 0; e < 32; ++e) {
            float s = mv[tid * 33 + e];
            if (s < worst) {
                float mx = tv[0];
                int pos = 0;
#pragma unroll
                for (int j = 1; j < 16; ++j) {
                    bool g = tv[j] > mx;
                    mx = g ? tv[j] : mx;
                    pos = g ? j : pos;
                }
#pragma unroll
                for (int j = 0; j < 16; ++j)
                    if (j == pos) { tv[j] = s; ti[j] = mi[tid * 33 + e]; }
                float nw = tv[0];
#pragma unroll
                for (int j = 1; j < 16; ++j) nw = fmaxf(nw, tv[j]);
                worst = nw;
            }
        }
        size_t oo = (size_t)row * KNN;
#pragma unroll
        for (int j = 0; j < 16; ++j) idx_out[oo + j] = ti[j];
    }
}

// ---------------------------------------------------------------------------
// K2: U = x @ (W1 - W2), V = x @ W2
// ---------------------------------------------------------------------------
__global__ void prep_UV(const float* __restrict__ x, const float* __restrict__ W,
                        float* __restrict__ U, float* __restrict__ V) {
    __shared__ float Ws[128][64];
    __shared__ float xs[4][64];
    int tid = threadIdx.x;
    for (int i = tid; i < 128 * 64; i += 256) ((float*)Ws)[i] = W[i];
    int p0 = blockIdx.x * 4;
    int r = tid >> 6, c = tid & 63;
    xs[r][c] = x[(size_t)(p0 + r) * C + c];
    __syncthreads();
    float u = 0.f, v = 0.f;
#pragma unroll
    for (int k = 0; k < 64; ++k) {
        float xv = xs[r][k];
        float w1 = Ws[k][c];
        float w2 = Ws[64 + k][c];
        u = fmaf(xv, w1 - w2, u);
        v = fmaf(xv, w2, v);
    }
    size_t o = (size_t)(p0 + r) * C + c;
    U[o] = u;
    V[o] = v;
}

// ---------------------------------------------------------------------------
// K3: BN stats
// ---------------------------------------------------------------------------
__global__ void stats_kernel(const float* __restrict__ U, const float* __restrict__ V,
                             const float* __restrict__ bias, const int* __restrict__ idx,
                             float* __restrict__ stats) {
    int tid = threadIdx.x;
    int c = tid & 63, kk = tid >> 6;
    int p0 = blockIdx.x * 32;
    float bc = bias[c];
    float sum = 0.f, sumsq = 0.f;
    for (int pp = 0; pp < 32; ++pp) {
        int p = p0 + pp;
        float u = U[(size_t)p * C + c] + bc;
#pragma unroll
        for (int k4 = 0; k4 < 4; ++k4) {
            int j = idx[(size_t)p * KNN + kk * 4 + k4];
            float h = u + V[(size_t)j * C + c];
            sum += h;
            sumsq = fmaf(h, h, sumsq);
        }
    }
    __shared__ float red[2][4][64];
    red[0][kk][c] = sum;
    red[1][kk][c] = sumsq;
    __syncthreads();
    if (tid < 64) {
        float s = red[0][0][tid] + red[0][1][tid] + red[0][2][tid] + red[0][3][tid];
        atomicAdd(&stats[tid], s);
    } else if (tid < 128) {
        int cc = tid - 64;
        float s = red[1][0][cc] + red[1][1][cc] + red[1][2][cc] + red[1][3][cc];
        atomicAdd(&stats[64 + cc], s);
    }
}

__global__ void finalize_kernel(const float* __restrict__ stats,
                                const float* __restrict__ gamma,
                                const float* __restrict__ beta,
                                float* __restrict__ sshift) {
    int c = threadIdx.x;
    const float N = (float)NEDGE;
    float mean = stats[c] / N;
    float var = stats[64 + c] / N - mean * mean;
    float s = gamma[c] * rsqrtf(var + EPSV);
    sshift[c] = s;
    sshift[64 + c] = beta[c] - mean * s;
}

// ---------------------------------------------------------------------------
// K5: out = lrelu(s*(U+b + max/min_k V[idx]) + t)  (monotone fusion of max_k)
// ---------------------------------------------------------------------------
__global__ void out_kernel(const float* __restrict__ U, const float* __restrict__ V,
                           const float* __restrict__ bias, const int* __restrict__ idx,
                           const float* __restrict__ sshift, float* __restrict__ out) {
    int tid = threadIdx.x;
    int c = tid & 63, g = tid >> 6;
    int p0 = blockIdx.x * 16;
    float s = sshift[c], t = sshift[64 + c];
    float bc = bias[c];
    for (int pp = g; pp < 16; pp += 4) {
        int p = p0 + pp;
        float mx = -FLT_MAX, mn = FLT_MAX;
#pragma unroll
        for (int k = 0; k < KNN; ++k) {
            int j = idx[(size_t)p * KNN + k];
            float v = V[(size_t)j * C + c];
            mx = fmaxf(mx, v);
            mn = fminf(mn, v);
        }
        float hsel = (s >= 0.f) ? mx : mn;
        float hn = fmaf(s, U[(size_t)p * C + c] + bc + hsel, t);
        out[(size_t)p * C + c] = (hn >= 0.f) ? hn : SLOPE * hn;
    }
}

// ---------------------------------------------------------------------------
extern "C" void kernel_launch(void* const* d_in, const int* in_sizes, int n_in,
                              void* d_out, int out_size, void* d_ws, size_t ws_size,
                              hipStream_t stream) {
    const float* x     = (const float*)d_in[0];
    const float* W     = (const float*)d_in[2];
    const float* bias  = (const float*)d_in[3];
    const float* gamma = (const float*)d_in[4];
    const float* beta  = (const float*)d_in[5];
    float* out = (float*)d_out;

    float* wsf    = (float*)d_ws;
    float* U      = wsf;
    float* V      = wsf + 2097152;
    uint4* xfh    = (uint4*)wsf;                   // aliases U/V, dead after knn
    uint4* xfm    = (uint4*)(wsf + 1048576);
    uint4* xfl    = (uint4*)(wsf + 2097152);
    float* sq     = wsf + 4194304;
    float* stats  = wsf + 4227072;
    float* sshift = wsf + 4227200;
    int*   idx    = (int*)(wsf + 4227328);
    float* pv     = wsf + 4751616;
    int*   pi     = (int*)(wsf + 5800192);

    hipLaunchKernelGGL(prep_frag, dim3(NPTS / 32), dim3(256), 0, stream, x, xfh, xfm, xfl, sq);
    hipLaunchKernelGGL(knn_kernel, dim3(BATCH * (P / 64) * NQ), dim3(256), 0, stream,
                       (const uint4*)xfh, (const uint4*)xfm, (const uint4*)xfl, sq, pv, pi);
    hipLaunchKernelGGL(merge_kernel, dim3(NPTS / 128), dim3(256), 0, stream, pv, pi, idx);
    hipLaunchKernelGGL(prep_UV, dim3(NPTS / 4), dim3(256), 0, stream, x, W, U, V);
    hipMemsetAsync(stats, 0, 128 * sizeof(float), stream);
    hipLaunchKernelGGL(stats_kernel, dim3(NPTS / 32), dim3(256), 0, stream, U, V, bias, idx, stats);
    hipLaunchKernelGGL(finalize_kernel, dim3(1), dim3(64), 0, stream, stats, gamma, beta, sshift);
    hipLaunchKernelGGL(out_kernel, dim3(NPTS / 16), dim3(256), 0, stream, U, V, bias, idx, sshift, out);
}

// Round 2
// 599.192 us; speedup vs baseline: 1.1640x; 1.1640x over previous
//
#include <hip/hip_runtime.h>
#include <cfloat>

#define BATCH 4
#define P 8192
#define C 64
#define KNN 16
#define NPTS (BATCH * P)        // 32768
#define NEDGE (NPTS * KNN)      // 524288
#define EPSV 1e-5f
#define SLOPE 0.2f
#define NQ 2                    // column-range split per row-tile
#define QCOLS (P / NQ)          // 4096 cols per block
#define NCH (QCOLS / 64)        // 64 chunks
#define CAP 52                  // append slots per row per generation (mean ~16, +9 sigma)

typedef __attribute__((ext_vector_type(8))) short bf16x8;
typedef __attribute__((ext_vector_type(16))) float f32x16;

// ---------------- workspace layout (float element offsets) ----------------
// U      : [NPTS][C]   @ 0          (2097152)   written AFTER knn
// V      : [NPTS][C]   @ 2097152    (2097152)   written AFTER knn
// xfh/xfm/xfl bf16 frags alias U/V region (dead after knn)
// sq     : [NPTS]      @ 4194304    (32768)
// stats  : [128]       @ 4227072
// sshift : [128]       @ 4227200
// idx    : int[NEDGE]  @ 4227328    (524288)
// pv     : [NPTS][NQ][16] float @ 4751616 (1048576)
// pi     : [NPTS][NQ][16] int   @ 5800192 (1048576)
// total = 6848768 floats = 26.1 MB

__device__ __forceinline__ unsigned short f2bf(float f) {
    unsigned u = __float_as_uint(f);
    u += 0x7FFFu + ((u >> 16) & 1u);
    return (unsigned short)(u >> 16);
}
__device__ __forceinline__ float bf2f(unsigned short s) {
    return __uint_as_float(((unsigned)s) << 16);
}
// monotone float<->uint map: monof(a) < monof(b)  <=>  a < b (finite floats)
__device__ __forceinline__ unsigned monof(float f) {
    unsigned u = __float_as_uint(f);
    return u ^ ((unsigned)((int)u >> 31) | 0x80000000u);
}
__device__ __forceinline__ float invmonof(unsigned k) {
    unsigned u = (k & 0x80000000u) ? (k ^ 0x80000000u) : ~k;
    return __uint_as_float(u);
}

// ---------------------------------------------------------------------------
// K0: fragment-layout 3-way bf16 split of x + exact fp32 row norms.
// ---------------------------------------------------------------------------
__global__ void prep_frag(const float* __restrict__ x, uint4* __restrict__ xfh,
                          uint4* __restrict__ xfm, uint4* __restrict__ xfl,
                          float* __restrict__ sq) {
    __shared__ float part[32][9];
    int tid = threadIdx.x;
    int ptl = tid >> 3, j8 = tid & 7;
    int g = blockIdx.x;
    int p = g * 32 + ptl;
    const float4* xp = (const float4*)(x + (size_t)p * C + j8 * 8);
    float4 a = xp[0], b = xp[1];
    float v[8] = {a.x, a.y, a.z, a.w, b.x, b.y, b.z, b.w};
    unsigned short hs[8], ms[8], ls[8];
    float ssum = 0.f;
#pragma unroll
    for (int e = 0; e < 8; ++e) {
        float xv = v[e];
        ssum = fmaf(xv, xv, ssum);
        unsigned short h = f2bf(xv);
        float r1 = xv - bf2f(h);
        unsigned short m = f2bf(r1);
        float r2 = r1 - bf2f(m);
        unsigned short l = f2bf(r2);
        hs[e] = h; ms[e] = m; ls[e] = l;
    }
    int dst = (g * 4 + (j8 >> 1)) * 64 + ptl + 32 * (j8 & 1);
    uint4 ph, pm, pl;
    ph.x = (unsigned)hs[0] | ((unsigned)hs[1] << 16);
    ph.y = (unsigned)hs[2] | ((unsigned)hs[3] << 16);
    ph.z = (unsigned)hs[4] | ((unsigned)hs[5] << 16);
    ph.w = (unsigned)hs[6] | ((unsigned)hs[7] << 16);
    pm.x = (unsigned)ms[0] | ((unsigned)ms[1] << 16);
    pm.y = (unsigned)ms[2] | ((unsigned)ms[3] << 16);
    pm.z = (unsigned)ms[4] | ((unsigned)ms[5] << 16);
    pm.w = (unsigned)ms[6] | ((unsigned)ms[7] << 16);
    pl.x = (unsigned)ls[0] | ((unsigned)ls[1] << 16);
    pl.y = (unsigned)ls[2] | ((unsigned)ls[3] << 16);
    pl.z = (unsigned)ls[4] | ((unsigned)ls[5] << 16);
    pl.w = (unsigned)ls[6] | ((unsigned)ls[7] << 16);
    xfh[dst] = ph; xfm[dst] = pm; xfl[dst] = pl;
    part[ptl][j8] = ssum;
    __syncthreads();
    if (j8 == 0) {
        float s = 0.f;
#pragma unroll
        for (int k = 0; k < 8; ++k) s += part[ptl][k];
        sq[p] = s;
    }
}

// ---------------------------------------------------------------------------
// K1: KNN, generation-batched rank selection (r8).
//
// r7 post-mortem: incremental per-candidate top-16 inserts (~90 VALU each,
// divergence-spread 3-4x/chunk) + 128 barriers/block were ~70% of knn time;
// shfl-chain variant (r7) made it worse (DS-pipe latency chain).
//
// r8: NO incremental maintenance. Per row keep only:
//   * topk[row][16]  : u64 keys (mono(value)<<32 | col_id), rank-ordered
//   * bufk[row][CAP] : appended candidate keys (atomic slot counter)
//   * worstL[row]    : float threshold = current 16th-smallest value
// Chunks append candidates with s < worstL (stale within a generation).
// At boundary chunks {0,1,3,7,15,31,63} ((c&(c+1))==0), one rank-based
// reselect: 64 lanes own the 16+n union elements, rank = #{smaller keys}
// via single u64 compares (ties exact via id in key: lowest id first, same
// as jax top_k); rank<16 writes slot rank. Columns-seen doubles each
// generation => E[appends/row/gen] ~= 16 (distribution-free), sigma~3.5,
// CAP=52 is +9 sigma; slot clamp keeps overflow memory-safe.
// Chunk 0 bootstraps through the same path: its 64 scores are slotted
// directly as 16 topk + 48 bufk entries, then reselect with n=48.
// Barriers: 14/block (2 per boundary) vs 128 — chunks inside a generation
// run barrier-free (atomic appends only), so waves drift and overlap.
// LDS = 26624 + 8192 + 256 + 256 = 35328 B -> 4 blocks/CU.
// ---------------------------------------------------------------------------
__global__ __launch_bounds__(256, 4) void knn_kernel(const uint4* __restrict__ xfh,
                                                     const uint4* __restrict__ xfm,
                                                     const uint4* __restrict__ xfl,
                                                     const float* __restrict__ sq,
                                                     float* __restrict__ pv,
                                                     int* __restrict__ pi) {
    __shared__ unsigned long long bufk[64 * CAP];  // append buffer (keys)
    __shared__ unsigned long long topk[64 * 16];   // current top-16 keys, rank-ordered
    __shared__ float worstL[64];
    __shared__ int   cnt[64];

    int tid = threadIdx.x;
    int b = blockIdx.x & 3;              // batch -> XCDs {b, b+4}: frags L2-resident
    int t = blockIdx.x >> 2;
    int tile = t & 127;
    int half = t >> 7;
    int bglob = b * P;
    int r0 = tile * 64;
    int colbase = half * QCOLS;
    int w = tid >> 6, lane = tid & 63;
    int wr = w & 1, wc = w >> 1;

    if (tid < 64) cnt[tid] = 0;

    // persistent A fragments for this wave's 32 rows
    int gA = ((bglob + r0) >> 5) + wr;
    bf16x8 Ah[4], Am[4], Al[4];
#pragma unroll
    for (int kk = 0; kk < 4; ++kk) {
        Ah[kk] = __builtin_bit_cast(bf16x8, xfh[(gA * 4 + kk) * 64 + lane]);
        Am[kk] = __builtin_bit_cast(bf16x8, xfm[(gA * 4 + kk) * 64 + lane]);
        Al[kk] = __builtin_bit_cast(bf16x8, xfl[(gA * 4 + kk) * 64 + lane]);
    }

    int rbase = wr * 32 + 4 * (lane >> 5);   // row of reg: rbase+(reg&3)+8*(reg>>2)
    int colq = wc * 32 + (lane & 31);        // this lane's column within chunk

    for (int chunk = 0; chunk < NCH; ++chunk) {
        int c0 = colbase + chunk * 64;
        int gB = ((bglob + c0) >> 5) + wc;
        bf16x8 Bh[4], Bm[4], Bl[4];
#pragma unroll
        for (int kk = 0; kk < 4; ++kk) {
            Bh[kk] = __builtin_bit_cast(bf16x8, xfh[(gB * 4 + kk) * 64 + lane]);
            Bm[kk] = __builtin_bit_cast(bf16x8, xfm[(gB * 4 + kk) * 64 + lane]);
            Bl[kk] = __builtin_bit_cast(bf16x8, xfl[(gB * 4 + kk) * 64 + lane]);
        }
        float sc = sq[bglob + c0 + colq];

        f32x16 acc0, acc1;
#pragma unroll
        for (int i = 0; i < 16; ++i) { acc0[i] = 0.f; acc1[i] = 0.f; }
#pragma unroll
        for (int kk = 0; kk < 4; ++kk) {
            acc0 = __builtin_amdgcn_mfma_f32_32x32x16_bf16(Ah[kk], Bh[kk], acc0, 0, 0, 0);
            acc1 = __builtin_amdgcn_mfma_f32_32x32x16_bf16(Ah[kk], Bm[kk], acc1, 0, 0, 0);
            acc0 = __builtin_amdgcn_mfma_f32_32x32x16_bf16(Am[kk], Bh[kk], acc0, 0, 0, 0);
            acc1 = __builtin_amdgcn_mfma_f32_32x32x16_bf16(Am[kk], Bm[kk], acc1, 0, 0, 0);
            acc0 = __builtin_amdgcn_mfma_f32_32x32x16_bf16(Ah[kk], Bl[kk], acc0, 0, 0, 0);
            acc1 = __builtin_amdgcn_mfma_f32_32x32x16_bf16(Al[kk], Bh[kk], acc1, 0, 0, 0);
        }

        int colg = bglob + c0 + colq;
        if (chunk == 0) {
            // bootstrap: slot the 64 chunk-0 scores directly as 16 top + 48 buf
#pragma unroll
            for (int reg = 0; reg < 16; ++reg) {
                float s = fmaf(-2.f, acc0[reg] + acc1[reg], sc);
                int row = rbase + (reg & 3) + 8 * (reg >> 2);
                unsigned long long key =
                    ((unsigned long long)monof(s) << 32) | (unsigned)colg;
                if (colq < 16) topk[row * 16 + colq] = key;
                else           bufk[row * CAP + (colq - 16)] = key;
            }
        } else {
            // thresholds for this wave's 16 distinct rows (broadcast b128 reads;
            // worstL is stable within a generation)
            float4 twA[4];
#pragma unroll
            for (int g4 = 0; g4 < 4; ++g4)
                twA[g4] = *(const float4*)&worstL[rbase + 8 * g4];
#pragma unroll
            for (int reg = 0; reg < 16; ++reg) {
                float s = fmaf(-2.f, acc0[reg] + acc1[reg], sc);
                float tW = ((const float*)&twA[reg >> 2])[reg & 3];
                if (s < tW) {
                    int row = rbase + (reg & 3) + 8 * (reg >> 2);
                    int slot = atomicAdd(&cnt[row], 1);
                    if (slot < CAP)
                        bufk[row * CAP + slot] =
                            ((unsigned long long)monof(s) << 32) | (unsigned)colg;
                }
            }
        }

        // ---- generation boundary: rank-based reselect (chunks 0,1,3,7,15,31,63)
        if ((chunk & (chunk + 1)) == 0) {
            __syncthreads();   // appends visible
            for (int rr = 0; rr < 16; ++rr) {
                int row = w * 16 + rr;
                int n = (chunk == 0) ? 48 : (cnt[row] < CAP ? cnt[row] : CAP);
                unsigned long long mykey;
                if (lane < 16)            mykey = topk[row * 16 + lane];
                else if (lane < 16 + n)   mykey = bufk[row * CAP + (lane - 16)];
                else                      mykey = ~0ull;   // rank >= 16+n, never writes
                int rank = 0;
#pragma unroll
                for (int j = 0; j < 16; ++j)
                    rank += (topk[row * 16 + j] < mykey) ? 1 : 0;
                for (int j = 0; j < n; ++j)
                    rank += (bufk[row * CAP + j] < mykey) ? 1 : 0;
                // keys distinct (id in low bits) => ranks distinct; exactly 16 win
                if (rank < 16) topk[row * 16 + rank] = mykey;
                if (rank == 15) worstL[row] = invmonof((unsigned)(mykey >> 32));
                if (lane == 0) cnt[row] = 0;
            }
            __syncthreads();   // topk/worstL stable, buffer free
        }
    }

    // ---- output: topk is rank-ordered; lanes 0-15 write each owned row ----
    for (int rr = 0; rr < 16; ++rr) {
        int row = w * 16 + rr;
        if (lane < 16) {
            unsigned long long k = topk[row * 16 + lane];
            size_t o = (((size_t)(bglob + r0 + row)) * NQ + half) * KNN;
            pv[o + lane] = invmonof((unsigned)(k >> 32));
            pi[o + lane] = (int)(unsigned)(k & 0xFFFFFFFFu);
        }
    }
}

// ---------------------------------------------------------------------------
// K1b: merge NQ=2 partial top-16 lists per row -> final idx.
// ---------------------------------------------------------------------------
__global__ void merge_kernel(const float* __restrict__ pv, const int* __restrict__ pi,
                             int* __restrict__ idx_out) {
    __shared__ float mv[128 * 33];
    __shared__ int   mi[128 * 33];
    int tid = threadIdx.x;
    int lr = tid & 127, q = tid >> 7;
    int row = blockIdx.x * 128 + lr;
    size_t o = ((size_t)row * NQ + q) * KNN;
#pragma unroll
    for (int j = 0; j < 16; ++j) {
        mv[lr * 33 + q * 16 + j] = pv[o + j];
        mi[lr * 33 + q * 16 + j] = pi[o + j];
    }
    __syncthreads();
    if (tid < 128) {
        float tv[16];
        int ti[16];
        float worst = FLT_MAX;
#pragma unroll
        for (int j = 0; j < 16; ++j) { tv[j] = FLT_MAX; ti[j] = 0; }
        for (int e = 0; e < 32; ++e) {
            float s = mv[tid * 33 + e];
            if (s < worst) {
                float mx = tv[0];
                int pos = 0;
#pragma unroll
                for (int j = 1; j < 16; ++j) {
                    bool g = tv[j] > mx;
                    mx = g ? tv[j] : mx;
                    pos = g ? j : pos;
                }
#pragma unroll
                for (int j = 0; j < 16; ++j)
                    if (j == pos) { tv[j] = s; ti[j] = mi[tid * 33 + e]; }
                float nw = tv[0];
#pragma unroll
                for (int j = 1; j < 16; ++j) nw = fmaxf(nw, tv[j]);
                worst = nw;
            }
        }
        size_t oo = (size_t)row * KNN;
#pragma unroll
        for (int j = 0; j < 16; ++j) idx_out[oo + j] = ti[j];
    }
}

// ---------------------------------------------------------------------------
// K2: U = x @ (W1 - W2), V = x @ W2
// ---------------------------------------------------------------------------
__global__ void prep_UV(const float* __restrict__ x, const float* __restrict__ W,
                        float* __restrict__ U, float* __restrict__ V) {
    __shared__ float Ws[128][64];
    __shared__ float xs[4][64];
    int tid = threadIdx.x;
    for (int i = tid; i < 128 * 64; i += 256) ((float*)Ws)[i] = W[i];
    int p0 = blockIdx.x * 4;
    int r = tid >> 6, c = tid & 63;
    xs[r][c] = x[(size_t)(p0 + r) * C + c];
    __syncthreads();
    float u = 0.f, v = 0.f;
#pragma unroll
    for (int k = 0; k < 64; ++k) {
        float xv = xs[r][k];
        float w1 = Ws[k][c];
        float w2 = Ws[64 + k][c];
        u = fmaf(xv, w1 - w2, u);
        v = fmaf(xv, w2, v);
    }
    size_t o = (size_t)(p0 + r) * C + c;
    U[o] = u;
    V[o] = v;
}

// ---------------------------------------------------------------------------
// K3: BN stats
// ---------------------------------------------------------------------------
__global__ void stats_kernel(const float* __restrict__ U, const float* __restrict__ V,
                             const float* __restrict__ bias, const int* __restrict__ idx,
                             float* __restrict__ stats) {
    int tid = threadIdx.x;
    int c = tid & 63, kk = tid >> 6;
    int p0 = blockIdx.x * 32;
    float bc = bias[c];
    float sum = 0.f, sumsq = 0.f;
    for (int pp = 0; pp < 32; ++pp) {
        int p = p0 + pp;
        float u = U[(size_t)p * C + c] + bc;
#pragma unroll
        for (int k4 = 0; k4 < 4; ++k4) {
            int j = idx[(size_t)p * KNN + kk * 4 + k4];
            float h = u + V[(size_t)j * C + c];
            sum += h;
            sumsq = fmaf(h, h, sumsq);
        }
    }
    __shared__ float red[2][4][64];
    red[0][kk][c] = sum;
    red[1][kk][c] = sumsq;
    __syncthreads();
    if (tid < 64) {
        float s = red[0][0][tid] + red[0][1][tid] + red[0][2][tid] + red[0][3][tid];
        atomicAdd(&stats[tid], s);
    } else if (tid < 128) {
        int cc = tid - 64;
        float s = red[1][0][cc] + red[1][1][cc] + red[1][2][cc] + red[1][3][cc];
        atomicAdd(&stats[64 + cc], s);
    }
}

__global__ void finalize_kernel(const float* __restrict__ stats,
                                const float* __restrict__ gamma,
                                const float* __restrict__ beta,
                                float* __restrict__ sshift) {
    int c = threadIdx.x;
    const float N = (float)NEDGE;
    float mean = stats[c] / N;
    float var = stats[64 + c] / N - mean * mean;
    float s = gamma[c] * rsqrtf(var + EPSV);
    sshift[c] = s;
    sshift[64 + c] = beta[c] - mean * s;
}

// ---------------------------------------------------------------------------
// K5: out = lrelu(s*(U+b + max/min_k V[idx]) + t)  (monotone fusion of max_k)
// ---------------------------------------------------------------------------
__global__ void out_kernel(const float* __restrict__ U, const float* __restrict__ V,
                           const float* __restrict__ bias, const int* __restrict__ idx,
                           const float* __restrict__ sshift, float* __restrict__ out) {
    int tid = threadIdx.x;
    int c = tid & 63, g = tid >> 6;
    int p0 = blockIdx.x * 16;
    float s = sshift[c], t = sshift[64 + c];
    float bc = bias[c];
    for (int pp = g; pp < 16; pp += 4) {
        int p = p0 + pp;
        float mx = -FLT_MAX, mn = FLT_MAX;
#pragma unroll
        for (int k = 0; k < KNN; ++k) {
            int j = idx[(size_t)p * KNN + k];
            float v = V[(size_t)j * C + c];
            mx = fmaxf(mx, v);
            mn = fminf(mn, v);
        }
        float hsel = (s >= 0.f) ? mx : mn;
        float hn = fmaf(s, U[(size_t)p * C + c] + bc + hsel, t);
        out[(size_t)p * C + c] = (hn >= 0.f) ? hn : SLOPE * hn;
    }
}

// ---------------------------------------------------------------------------
extern "C" void kernel_launch(void* const* d_in, const int* in_sizes, int n_in,
                              void* d_out, int out_size, void* d_ws, size_t ws_size,
                              hipStream_t stream) {
    const float* x     = (const float*)d_in[0];
    const float* W     = (const float*)d_in[2];
    const float* bias  = (const float*)d_in[3];
    const float* gamma = (const float*)d_in[4];
    const float* beta  = (const float*)d_in[5];
    float* out = (float*)d_out;

    float* wsf    = (float*)d_ws;
    float* U      = wsf;
    float* V      = wsf + 2097152;
    uint4* xfh    = (uint4*)wsf;                   // aliases U/V, dead after knn
    uint4* xfm    = (uint4*)(wsf + 1048576);
    uint4* xfl    = (uint4*)(wsf + 2097152);
    float* sq     = wsf + 4194304;
    float* stats  = wsf + 4227072;
    float* sshift = wsf + 4227200;
    int*   idx    = (int*)(wsf + 4227328);
    float* pv     = wsf + 4751616;
    int*   pi     = (int*)(wsf + 5800192);

    hipLaunchKernelGGL(prep_frag, dim3(NPTS / 32), dim3(256), 0, stream, x, xfh, xfm, xfl, sq);
    hipLaunchKernelGGL(knn_kernel, dim3(BATCH * (P / 64) * NQ), dim3(256), 0, stream,
                       (const uint4*)xfh, (const uint4*)xfm, (const uint4*)xfl, sq, pv, pi);
    hipLaunchKernelGGL(merge_kernel, dim3(NPTS / 128), dim3(256), 0, stream, pv, pi, idx);
    hipLaunchKernelGGL(prep_UV, dim3(NPTS / 4), dim3(256), 0, stream, x, W, U, V);
    hipMemsetAsync(stats, 0, 128 * sizeof(float), stream);
    hipLaunchKernelGGL(stats_kernel, dim3(NPTS / 32), dim3(256), 0, stream, U, V, bias, idx, stats);
    hipLaunchKernelGGL(finalize_kernel, dim3(1), dim3(64), 0, stream, stats, gamma, beta, sshift);
    hipLaunchKernelGGL(out_kernel, dim3(NPTS / 16), dim3(256), 0, stream, U, V, bias, idx, sshift, out);
}